// Round 4
// baseline (358.440 us; speedup 1.0000x reference)
//
#include <hip/hip_runtime.h>
#include <math.h>

// Problem constants
#define K_    1024
#define N_    32768
#define NELEM 8388608

// d_out layout (floats, reference return order)
#define Q_OFF    1
#define PERP_OFF 8388609
#define IDX_OFF  8388610

// d_out Q-region scratch (overwritten by k_gather at the end; 16B-aligned bases)
#define XLO_F_OFF 4          // xlo: 32768*256 fp16
#define ELO_F_OFF 4194308    // elo: 1024*256 fp16

typedef unsigned long long ull;
typedef _Float16 h8  __attribute__((ext_vector_type(8)));
typedef float    f4v __attribute__((ext_vector_type(4)));

// ws layout (bytes)
#define WS_COUNTS  0        // 1024 u32
#define WS_SUMSQ   4096     // double
#define WS_RISKCNT 4104     // u32
#define WS_DONE    4108     // u32
#define WS_EN2     4160     // 1024 f32
#define WS_XN2     8256     // 32768 f32
#define WS_IDX     139328   // 32768 i32
#define WS_RLIST   270400   // 32768 i32
#define WS_RKEY    401472   // 32768 u64
#define WS_EHI     663616   // 1024*256 fp16
#define WS_XHI     1187904  // 32768*256 fp16 (pixel-major)

// risky-gap threshold (scaled-by-1024 domain); validated in round 3.
#define SWEEP_W 0.15f

__device__ __forceinline__ unsigned ordfix(unsigned u) {
    return u ^ ((u & 0x80000000u) ? 0xFFFFFFFFu : 0x80000000u);
}
__device__ __forceinline__ unsigned ordunfix(unsigned u) {
    return (u & 0x80000000u) ? (u ^ 0x80000000u) : ~u;
}

// ---------------------------------------------------------------------------
// k_pre: fused. blocks 0..511: x transpose -> xhi/xlo + xn2.
//        blocks 512..527: codebook -> ehi/elo + en2.
//        blocks 528..591: rkey init (+ block 528: counts/rcnt/done/sumsq zero).
__global__ __launch_bounds__(256) void k_pre(const float* __restrict__ x,
                                             const float* __restrict__ cb,
                                             ushort* __restrict__ xhi,
                                             ushort* __restrict__ xlo,
                                             float* __restrict__ xn2,
                                             ushort* __restrict__ ehi,
                                             ushort* __restrict__ elo,
                                             float* __restrict__ en2,
                                             ull* __restrict__ rkey,
                                             unsigned* __restrict__ counts,
                                             unsigned* __restrict__ rcnt,
                                             unsigned* __restrict__ done,
                                             double* __restrict__ sumsq) {
    __shared__ float T[256 * 68];
    __shared__ double red[256];
    const int t = threadIdx.x, bid = blockIdx.x;

    if (bid < 512) {
        // ---- prep: 64 contiguous pixels -> pixel-major fp16 hi/lo + xn2 ----
        const int b = bid >> 4, hw0 = (bid & 15) << 6;
        const float* xb = x + b * 262144 + hw0;
#pragma unroll
        for (int i = 0; i < 16; ++i) {
            const int jv = i * 256 + t, c = jv >> 4, p4 = (jv & 15) << 2;
            *(float4*)(&T[c * 68 + p4]) = *(const float4*)(xb + c * 1024 + p4);
        }
        __syncthreads();
        const int p = t >> 2, q = t & 3;
        ushort* oh = xhi + (size_t)(bid * 64 + p) * 256 + q * 64;
        ushort* ol = xlo + (size_t)(bid * 64 + p) * 256 + q * 64;
        double sn = 0.0;
#pragma unroll
        for (int g = 0; g < 8; ++g) {
            union { _Float16 h[8]; int4 v; } ph, pl;
#pragma unroll
            for (int j = 0; j < 8; ++j) {
                const float v = T[(q * 64 + g * 8 + j) * 68 + p];
                sn += (double)v * v;
                const _Float16 hi = (_Float16)v;
                ph.h[j] = hi;
                pl.h[j] = (_Float16)((v - (float)hi) * 2048.0f);
            }
            *(int4*)(oh + g * 8) = ph.v;
            *(int4*)(ol + g * 8) = pl.v;
        }
        red[t] = sn;
        __syncthreads();
        if (t < 64)
            xn2[bid * 64 + t] = (float)(red[t * 4] + red[t * 4 + 1] +
                                        red[t * 4 + 2] + red[t * 4 + 3]);
    } else if (bid < 528) {
        // ---- ecvt: codebook hi/lo + row norms ----
        const int row = (bid - 512) * 64 + (t >> 2);
        const int seg = t & 3;
        const float* src = cb + (size_t)row * 256 + seg * 64;
        ushort* dh = ehi + (size_t)row * 256 + seg * 64;
        ushort* dl = elo + (size_t)row * 256 + seg * 64;
        double s = 0.0;
#pragma unroll
        for (int i = 0; i < 8; ++i) {
            const float4 a = *(const float4*)(src + i * 8);
            const float4 b = *(const float4*)(src + i * 8 + 4);
            s += (double)a.x * a.x + (double)a.y * a.y + (double)a.z * a.z + (double)a.w * a.w;
            s += (double)b.x * b.x + (double)b.y * b.y + (double)b.z * b.z + (double)b.w * b.w;
            float v[8] = {a.x, a.y, a.z, a.w, b.x, b.y, b.z, b.w};
            union { _Float16 h[8]; int4 q; } ph, pl;
#pragma unroll
            for (int j = 0; j < 8; ++j) {
                const float es = v[j] * 1024.0f;
                const _Float16 hi = (_Float16)es;
                ph.h[j] = hi;
                pl.h[j] = (_Float16)((es - (float)hi) * 2048.0f);
            }
            *(int4*)(dh + i * 8) = ph.q;
            *(int4*)(dl + i * 8) = pl.q;
        }
        red[t] = s;
        __syncthreads();
        if (t < 64) {
            const int r2 = (bid - 512) * 64 + t;
            en2[r2] = (float)(red[t * 4] + red[t * 4 + 1] + red[t * 4 + 2] + red[t * 4 + 3]);
        }
    } else {
        // ---- init: rkey = +inf; counts/rcnt/done/sumsq = 0 ----
        const int ib = bid - 528;
        const int i0 = ib * 512 + t * 2;
        rkey[i0] = ~0ull; rkey[i0 + 1] = ~0ull;
        if (ib == 0) {
            ((uint4*)counts)[t] = make_uint4(0u, 0u, 0u, 0u);
            if (t == 0) { *rcnt = 0u; *done = 0u; *sumsq = 0.0; }
        }
    }
}

// ---------------------------------------------------------------------------
// Split-fp16 MFMA sweep, barrier-free K-loop: A and B fragments both loaded
// directly from global (L1/L2-hot). Block = 64 px x 1024 codes (kt: 4 x 256);
// wave w covers 64 px x 64 codes per kt. Epilogue (Ds dump + scan) unchanged.
__global__ __launch_bounds__(256, 2) void k_sweep(const ushort* __restrict__ xhi,
                                                  const ushort* __restrict__ xlo,
                                                  const ushort* __restrict__ ehi,
                                                  const ushort* __restrict__ elo,
                                                  const float* __restrict__ en2,
                                                  int* __restrict__ idxv,
                                                  int* __restrict__ rlist,
                                                  unsigned* __restrict__ rcnt) {
    __shared__ float Ds[128 * 64];     // 32 KB half-dump (xor-swizzled px)
    __shared__ float enSs[256];
    __shared__ ull   ltop[256][2];
    __shared__ ull   top2a[64], top2b[64];

    const int t = threadIdx.x, bid = blockIdx.x;
    const int p0 = bid << 6;
    const int w = t >> 6, lane = t & 63;
    const int quad = lane >> 4, l15 = lane & 15;

    if (t < 64) { top2a[t] = ~0ull; top2b[t] = ~0ull; }

    for (int kt = 0; kt < 4; ++kt) {
        enSs[t] = en2[kt * 256 + t] * 1024.0f;   // consumed after epilogue barriers
        const f4v z = {0.f, 0.f, 0.f, 0.f};
        f4v acc1[4][4], acc2[4][4];
#pragma unroll
        for (int mi = 0; mi < 4; ++mi)
#pragma unroll
            for (int ni = 0; ni < 4; ++ni) { acc1[mi][ni] = z; acc2[mi][ni] = z; }

#pragma unroll 2
        for (int dc = 0; dc < 8; ++dc) {
            h8 ah[4], al[4], bh[4], bl[4];
#pragma unroll
            for (int mi = 0; mi < 4; ++mi) {
                const size_t arow = (size_t)(p0 + mi * 16 + l15) * 256 + dc * 32 + quad * 8;
                ah[mi] = *(const h8*)(xhi + arow);
                al[mi] = *(const h8*)(xlo + arow);
            }
#pragma unroll
            for (int ni = 0; ni < 4; ++ni) {
                const size_t brow = (size_t)(kt * 256 + w * 64 + ni * 16 + l15) * 256 +
                                    dc * 32 + quad * 8;
                bh[ni] = *(const h8*)(ehi + brow);
                bl[ni] = *(const h8*)(elo + brow);
            }
#pragma unroll
            for (int mi = 0; mi < 4; ++mi)
#pragma unroll
                for (int ni = 0; ni < 4; ++ni) {
                    acc1[mi][ni] = __builtin_amdgcn_mfma_f32_16x16x32_f16(
                        ah[mi], bh[ni], acc1[mi][ni], 0, 0, 0);
                    acc2[mi][ni] = __builtin_amdgcn_mfma_f32_16x16x32_f16(
                        ah[mi], bl[ni], acc2[mi][ni], 0, 0, 0);
                    acc2[mi][ni] = __builtin_amdgcn_mfma_f32_16x16x32_f16(
                        al[mi], bh[ni], acc2[mi][ni], 0, 0, 0);
                }
        }
        // epilogue: two 128-code halves
#pragma unroll
        for (int h = 0; h < 2; ++h) {
            __syncthreads();
            if ((w >> 1) == h) {
                const int wl = w & 1;
#pragma unroll
                for (int mi = 0; mi < 4; ++mi)
#pragma unroll
                    for (int ni = 0; ni < 4; ++ni) {
                        const f4v cmb = acc1[mi][ni] + acc2[mi][ni] * (1.0f / 2048.0f);
                        const int np = wl * 64 + ni * 16 + l15;
                        const int mb = mi * 16 + quad * 4;
                        const int grp = (mb >> 2) ^ (np & 15);
                        *(f4v*)(&Ds[np * 64 + grp * 4]) = cmb;
                    }
            }
            __syncthreads();
            {
                const int p = t & 63, cb0 = (t >> 6) * 32;
                ull k1 = ~0ull, k2 = ~0ull;
#pragma unroll 4
                for (int j = 0; j < 32; ++j) {
                    const int c = cb0 + j;
                    const int addr = c * 64 + ((((p >> 2) ^ (c & 15)) << 2) | (p & 3));
                    const float D = fmaf(-2.0f, Ds[addr], enSs[h * 128 + c]);
                    const ull key = ((ull)ordfix(__float_as_uint(D)) << 32) |
                                    (unsigned)(kt * 256 + h * 128 + c);
                    if (key < k1) { k2 = k1; k1 = key; }
                    else if (key < k2) k2 = key;
                }
                ltop[t][0] = k1; ltop[t][1] = k2;
            }
            __syncthreads();
            if (t < 64) {
                ull c1 = top2a[t], c2 = top2b[t];
#pragma unroll
                for (int s = 0; s < 4; ++s) {
                    const ull x1 = ltop[t + s * 64][0], x2 = ltop[t + s * 64][1];
                    if (x1 < c1) { c2 = c1; c1 = x1; } else if (x1 < c2) c2 = x1;
                    if (x2 < c1) { c2 = c1; c1 = x2; } else if (x2 < c2) c2 = x2;
                }
                top2a[t] = c1; top2b[t] = c2;
            }
            __syncthreads();
        }
    }
    if (t < 64) {
        const ull a = top2a[t], b2 = top2b[t];
        const int k1 = (int)(unsigned)(a & 0xffffffffu);
        const float D1 = __uint_as_float(ordunfix((unsigned)(a >> 32)));
        const float D2 = __uint_as_float(ordunfix((unsigned)(b2 >> 32)));
        const int P = p0 + t;
        idxv[P] = k1;
        const bool risky = (D2 - D1) <= SWEEP_W;
        const ull mask = __ballot(risky);
        const int pre = __popcll(mask & ((1ull << t) - 1ull));
        unsigned base = 0;
        if (t == 0) base = atomicAdd(rcnt, (unsigned)__popcll(mask));
        base = (unsigned)__shfl((int)base, 0, 64);
        if (risky) rlist[base + pre] = P;
    }
}

// ---------------------------------------------------------------------------
// Exact f32 rescan of risky pixels (validated: replicates np ref numerics).
__global__ __launch_bounds__(256) void k_rescan(const float* __restrict__ x,
                                                const float* __restrict__ cb,
                                                const float* __restrict__ en2,
                                                const float* __restrict__ xn2,
                                                const int* __restrict__ rlist,
                                                const unsigned* __restrict__ rcnt,
                                                ull* __restrict__ rkey) {
    __shared__ float xs[64 * 68];
    __shared__ float es[64 * 132];
    __shared__ int plist[64];
    const int t = threadIdx.x;
    const unsigned cnt = *rcnt;
    const int nunits = (int)(((cnt + 63) >> 6) << 3);
    const int ti = t >> 4, tj = t & 15;

    for (int u = blockIdx.x; u < nunits; u += gridDim.x) {
        const int tile = u >> 3, kt = u & 7;
        __syncthreads();
        if (t < 64) {
            const int li = tile * 64 + t;
            plist[t] = rlist[li < (int)cnt ? li : 0];
        }
        __syncthreads();

        float xnr[4]; int pid[4];
#pragma unroll
        for (int r = 0; r < 4; ++r) {
            pid[r] = plist[ti * 4 + r];
            xnr[r] = xn2[pid[r]];
        }
        float acc[4][8];
#pragma unroll
        for (int r = 0; r < 4; ++r)
#pragma unroll
            for (int j = 0; j < 8; ++j) acc[r][j] = 0.f;
        float best_s[4]; int best_k[4];
#pragma unroll
        for (int r = 0; r < 4; ++r) { best_s[r] = INFINITY; best_k[r] = 0; }

        for (int dc = 0; dc < 4; ++dc) {
            __syncthreads();
            {
                const int p = t & 63, coff = t >> 6;
                const int P = plist[p];
                const float* xp = x + ((P >> 10) * 262144 + (P & 1023));
#pragma unroll
                for (int cc = 0; cc < 16; ++cc) {
                    const int cl = coff * 16 + cc;
                    xs[cl * 68 + p] = xp[(dc * 64 + cl) * 1024];
                }
            }
#pragma unroll
            for (int i = 0; i < 8; ++i) {
                const int jv = i * 256 + t, k = jv >> 4, d4 = (jv & 15) << 2;
                const float4 v = *(const float4*)(cb + (size_t)(kt * 128 + k) * 256 + dc * 64 + d4);
                es[(d4 + 0) * 132 + k] = v.x; es[(d4 + 1) * 132 + k] = v.y;
                es[(d4 + 2) * 132 + k] = v.z; es[(d4 + 3) * 132 + k] = v.w;
            }
            __syncthreads();
#pragma unroll 4
            for (int d = 0; d < 64; ++d) {
                const float4 xv = *(const float4*)(&xs[d * 68 + ti * 4]);
                const float4 e0 = *(const float4*)(&es[d * 132 + tj * 8]);
                const float4 e1 = *(const float4*)(&es[d * 132 + tj * 8 + 4]);
                const float xr[4] = {xv.x, xv.y, xv.z, xv.w};
                const float ej[8] = {e0.x, e0.y, e0.z, e0.w, e1.x, e1.y, e1.z, e1.w};
#pragma unroll
                for (int r = 0; r < 4; ++r)
#pragma unroll
                    for (int j = 0; j < 8; ++j)
                        acc[r][j] = fmaf(xr[r], ej[j], acc[r][j]);
            }
        }
#pragma unroll
        for (int j = 0; j < 8; ++j) {
            const int k = kt * 128 + tj * 8 + j;
            const float en = en2[k];
#pragma unroll
            for (int r = 0; r < 4; ++r) {
                const float s1 = xnr[r] + en;
                const float dist = fmaf(-2.f, acc[r][j], s1);
                if (dist < best_s[r] || (dist == best_s[r] && k < best_k[r])) {
                    best_s[r] = dist; best_k[r] = k;
                }
            }
        }
#pragma unroll
        for (int r = 0; r < 4; ++r) {
            float s = best_s[r]; int k = best_k[r];
            for (int m = 1; m < 16; m <<= 1) {
                const float s2 = __shfl_xor(s, m, 64);
                const int k2 = __shfl_xor(k, m, 64);
                if (s2 < s || (s2 == s && k2 < k)) { s = s2; k = k2; }
            }
            if (tj == 0 && (tile * 64 + ti * 4 + r) < (int)cnt) {
                const ull key = ((ull)__float_as_uint(s) << 32) | (unsigned)k;  // dist>0
                atomicMin(&rkey[pid[r]], key);
            }
        }
    }
}

// ---------------------------------------------------------------------------
// Gather (+resolve fused) -> q_out, (q-x)^2 sum, histogram, idx_f; the LAST
// block (device-scope done-counter) computes loss + perplexity.
__global__ __launch_bounds__(256) void k_gather(const float* __restrict__ x,
                                                const float* __restrict__ cb,
                                                const int* __restrict__ idxv,
                                                const ull* __restrict__ rkey,
                                                float* __restrict__ out,
                                                double* __restrict__ sumsq,
                                                unsigned* __restrict__ counts,
                                                unsigned* __restrict__ done) {
    __shared__ __align__(16) float cs[32 * 260];
    __shared__ int   kidx[32];
    __shared__ float wpart[4];
    __shared__ int   lastf;
    __shared__ double part[256];

    const int t = threadIdx.x, bid = blockIdx.x;
    const int n0 = bid * 32;
    if (t < 32) {
        const int n = n0 + t;
        const ull rk = rkey[n];
        const int kk = (rk != ~0ull) ? (int)(unsigned)(rk & 0xffffffffu) : idxv[n];
        kidx[t] = kk;
        atomicAdd(&counts[kk], 1u);
        out[IDX_OFF + n] = (float)kk;
    }
    if (t == 0) lastf = 0;
    __syncthreads();
#pragma unroll
    for (int i = 0; i < 8; ++i) {
        int jv = (i << 8) + t;
        int p = jv >> 6, c4 = (jv & 63) << 2;
        const float4 v = *(const float4*)(cb + (size_t)kidx[p] * 256 + c4);
        *(float4*)(&cs[p * 260 + c4]) = v;
    }
    __syncthreads();

    const int b = bid >> 5, h = bid & 31;
    const float* xb = x + b * 262144 + h * 32;
    float* qb = out + Q_OFF + b * 262144 + h * 32;

    float local = 0.f;
#pragma unroll
    for (int i = 0; i < 8; ++i) {
        int j = (i << 8) + t;
        int c = j >> 3, w4 = (j & 7) << 2;
        const float q0 = cs[(w4 + 0) * 260 + c];
        const float q1 = cs[(w4 + 1) * 260 + c];
        const float q2 = cs[(w4 + 2) * 260 + c];
        const float q3 = cs[(w4 + 3) * 260 + c];
        const float4 xv = *(const float4*)(xb + c * 1024 + w4);
        const float d0 = q0 - xv.x, d1 = q1 - xv.y;
        const float d2 = q2 - xv.z, d3 = q3 - xv.w;
        local += d0 * d0 + d1 * d1 + d2 * d2 + d3 * d3;
        qb[c * 1024 + w4 + 0] = q0;
        qb[c * 1024 + w4 + 1] = q1;
        qb[c * 1024 + w4 + 2] = q2;
        qb[c * 1024 + w4 + 3] = q3;
    }
    for (int m = 32; m > 0; m >>= 1) local += __shfl_down(local, m, 64);
    if ((t & 63) == 0) wpart[t >> 6] = local;
    __syncthreads();
    if (t == 0) {
        const float bs = wpart[0] + wpart[1] + wpart[2] + wpart[3];
        atomicAdd(sumsq, (double)bs);
        __threadfence();
        if (atomicAdd(done, 1u) == 1023u) lastf = 1;
    }
    __syncthreads();
    if (lastf) {
        // all 1024 blocks' atomics are visible (fence + done handshake)
        double s = 0.0;
        for (int k = t; k < K_; k += 256) {
            const unsigned c = atomicAdd(&counts[k], 0u);   // coherent read
            const double p = (double)c / (double)N_;
            s += p * log(p + 1e-10);
        }
        part[t] = s;
        __syncthreads();
        for (int off = 128; off > 0; off >>= 1) {
            if (t < off) part[t] += part[t + off];
            __syncthreads();
        }
        if (t == 0) {
            const double ss = atomicAdd(sumsq, 0.0);        // coherent read
            out[PERP_OFF] = (float)exp(-part[0]);
            out[0] = (float)(ss * 1.25 / (double)NELEM);
        }
    }
}

// ---------------------------------------------------------------------------
extern "C" void kernel_launch(void* const* d_in, const int* in_sizes, int n_in,
                              void* d_out, int out_size, void* d_ws, size_t ws_size,
                              hipStream_t stream) {
    const float* x  = (const float*)d_in[0];
    const float* cb = (const float*)d_in[1];
    float* out = (float*)d_out;
    char*  ws  = (char*)d_ws;

    unsigned* counts = (unsigned*)(ws + WS_COUNTS);
    double*   sumsq  = (double*)(ws + WS_SUMSQ);
    unsigned* rcnt   = (unsigned*)(ws + WS_RISKCNT);
    unsigned* done   = (unsigned*)(ws + WS_DONE);
    float*    en2    = (float*)(ws + WS_EN2);
    float*    xn2    = (float*)(ws + WS_XN2);
    int*      idxv   = (int*)(ws + WS_IDX);
    int*      rlist  = (int*)(ws + WS_RLIST);
    ull*      rkey   = (ull*)(ws + WS_RKEY);
    ushort*   ehi    = (ushort*)(ws + WS_EHI);
    ushort*   xhi    = (ushort*)(ws + WS_XHI);
    ushort*   xlo    = (ushort*)(out + XLO_F_OFF);   // d_out Q region scratch
    ushort*   elo    = (ushort*)(out + ELO_F_OFF);

    k_pre<<<592, 256, 0, stream>>>(x, cb, xhi, xlo, xn2, ehi, elo, en2,
                                   rkey, counts, rcnt, done, sumsq);
    k_sweep<<<512, 256, 0, stream>>>(xhi, xlo, ehi, elo, en2, idxv, rlist, rcnt);
    k_rescan<<<512, 256, 0, stream>>>(x, cb, en2, xn2, rlist, rcnt, rkey);
    k_gather<<<1024, 256, 0, stream>>>(x, cb, idxv, rkey, out, sumsq, counts, done);
}

// Round 5
// 291.069 us; speedup vs baseline: 1.2315x; 1.2315x over previous
//
#include <hip/hip_runtime.h>
#include <math.h>

// Problem constants
#define K_    1024
#define N_    32768
#define NELEM 8388608

// d_out layout (floats, reference return order)
#define Q_OFF    1
#define PERP_OFF 8388609
#define IDX_OFF  8388610

// d_out Q-region scratch (overwritten by k_gather at the end)
#define XLO_F_OFF 4          // xlo frag: 32768*256 fp16
#define ELO_F_OFF 4194308    // elo frag: 1024*256 fp16

typedef unsigned long long ull;
typedef _Float16 h8  __attribute__((ext_vector_type(8)));
typedef float    f4v __attribute__((ext_vector_type(4)));

// ws layout (bytes)
#define WS_COUNTS  0        // 1024 u32
#define WS_SUMSQ   4096     // double
#define WS_RISKCNT 4104     // u32
#define WS_DONE    4108     // u32
#define WS_EN2     4160     // 1024 f32
#define WS_XN2     8256     // 32768 f32
#define WS_IDX     139328   // 32768 i32
#define WS_RLIST   270400   // 32768 i32
#define WS_RKEY    401472   // 32768 u64
#define WS_EHI     663616   // 1024*256 fp16 (fragment-major)
#define WS_XHI     1187904  // 32768*256 fp16 (fragment-major)

// risky-gap threshold (scaled-by-1024 domain); validated rounds 3-4.
#define SWEEP_W 0.15f

__device__ __forceinline__ unsigned ordfix(unsigned u) {
    return u ^ ((u & 0x80000000u) ? 0xFFFFFFFFu : 0x80000000u);
}
__device__ __forceinline__ unsigned ordunfix(unsigned u) {
    return (u & 0x80000000u) ? (u ^ 0x80000000u) : ~u;
}

// ---------------------------------------------------------------------------
// k_pre: blocks 0..511: x -> fragment-major fp16 hi/lo + xn2.
//        blocks 512..527: codebook -> fragment-major fp16 hi/lo + en2.
//        blocks 528..591: rkey init (+ block 528: counts/rcnt/done/sumsq).
// Fragment layout (halfwords):
//   xf: [pixblock 512][dc 8][mi 4][lane 64][j 8]; pixel=mi*16+(lane&15),
//       d = dc*32 + (lane>>4)*8 + j
//   ef: [kt 4][w 4][dc 8][ni 4][lane 64][j 8]; code=kt*256+w*64+ni*16+(lane&15)
__global__ __launch_bounds__(256) void k_pre(const float* __restrict__ x,
                                             const float* __restrict__ cb,
                                             ushort* __restrict__ xfh,
                                             ushort* __restrict__ xfl,
                                             float* __restrict__ xn2,
                                             ushort* __restrict__ efh,
                                             ushort* __restrict__ efl,
                                             float* __restrict__ en2,
                                             ull* __restrict__ rkey,
                                             unsigned* __restrict__ counts,
                                             unsigned* __restrict__ rcnt,
                                             unsigned* __restrict__ done,
                                             double* __restrict__ sumsq) {
    __shared__ float T[256 * 68];
    __shared__ double red[256];
    const int t = threadIdx.x, bid = blockIdx.x;

    if (bid < 512) {
        const int b = bid >> 4, hw0 = (bid & 15) << 6;
        const float* xb = x + b * 262144 + hw0;
        // stage [c][p], quad-swizzled so frag reads are <=2-way bank aliased
#pragma unroll
        for (int i = 0; i < 16; ++i) {
            const int jv = i * 256 + t, c = jv >> 4, p4 = (jv & 15) << 2;
            const int sw = ((c >> 3) & 3) << 3;
            *(float4*)(&T[c * 68 + (p4 ^ sw)]) = *(const float4*)(xb + c * 1024 + p4);
        }
        __syncthreads();
        const int mi = t >> 6, lane = t & 63;
        const int quad = (t >> 4) & 3, l15 = t & 15;
        const int pxs = (mi * 16 + l15) ^ (quad << 3);
        double sn = 0.0;
        const size_t obase = (size_t)bid * 16384 + lane * 8;
#pragma unroll
        for (int dc = 0; dc < 8; ++dc) {
            union { _Float16 h[8]; int4 v; } ph, pl;
#pragma unroll
            for (int j = 0; j < 8; ++j) {
                const float v = T[(dc * 32 + quad * 8 + j) * 68 + pxs];
                sn += (double)v * v;
                const _Float16 hi = (_Float16)v;
                ph.h[j] = hi;
                pl.h[j] = (_Float16)((v - (float)hi) * 2048.0f);
            }
            *(int4*)(xfh + obase + (dc * 4 + mi) * 512) = ph.v;
            *(int4*)(xfl + obase + (dc * 4 + mi) * 512) = pl.v;
        }
        red[t] = sn;
        __syncthreads();
        if (t < 64) {
            const int base = (t >> 4) * 64 + (t & 15);
            xn2[bid * 64 + t] = (float)(red[base] + red[base + 16] +
                                        red[base + 32] + red[base + 48]);
        }
    } else if (bid < 528) {
        const int n = (bid - 512) * 64 + (t >> 2);
        const int seg = t & 3;
        const float* src = cb + (size_t)n * 256 + seg * 64;
        const int kt = n >> 8, wch = (n >> 6) & 3, ni = (n >> 4) & 3, l15 = n & 15;
        double s = 0.0;
#pragma unroll
        for (int g = 0; g < 8; ++g) {
            const float4 a = *(const float4*)(src + g * 8);
            const float4 b = *(const float4*)(src + g * 8 + 4);
            s += (double)a.x * a.x + (double)a.y * a.y + (double)a.z * a.z + (double)a.w * a.w;
            s += (double)b.x * b.x + (double)b.y * b.y + (double)b.z * b.z + (double)b.w * b.w;
            const float v[8] = {a.x, a.y, a.z, a.w, b.x, b.y, b.z, b.w};
            union { _Float16 h[8]; int4 q; } ph, pl;
#pragma unroll
            for (int j = 0; j < 8; ++j) {
                const float es = v[j] * 1024.0f;               // exact (pow2)
                const _Float16 hi = (_Float16)es;
                ph.h[j] = hi;
                pl.h[j] = (_Float16)((es - (float)hi) * 2048.0f);
            }
            const int dc = seg * 2 + (g >> 2);
            const int quad = g & 3;
            const size_t addr = ((size_t)(((kt * 4 + wch) * 8 + dc) * 4 + ni) * 64 +
                                 (quad * 16 + l15)) * 8;
            *(int4*)(efh + addr) = ph.q;
            *(int4*)(efl + addr) = pl.q;
        }
        red[t] = s;
        __syncthreads();
        if (t < 64) {
            const int r2 = (bid - 512) * 64 + t;
            en2[r2] = (float)(red[t * 4] + red[t * 4 + 1] + red[t * 4 + 2] + red[t * 4 + 3]);
        }
    } else {
        const int ib = bid - 528;
        const int i0 = ib * 512 + t * 2;
        rkey[i0] = ~0ull; rkey[i0 + 1] = ~0ull;
        if (ib == 0) {
            ((uint4*)counts)[t] = make_uint4(0u, 0u, 0u, 0u);
            if (t == 0) { *rcnt = 0u; *done = 0u; *sumsq = 0.0; }
        }
    }
}

// ---------------------------------------------------------------------------
// Split-fp16 MFMA sweep. Block = 64 px x 1024 codes; wave w = 64 px x 64 codes
// per kt (4 x 256). A (hi+lo) staged ONCE in LDS (fragment-major, conflict-free
// ds_read_b128); B streams coalesced from L2. Zero barriers in the K-loop.
// Epilogue: full-256-code Ds dump + scan (r3-proven logic), 3 barriers/kt.
__global__ __launch_bounds__(256) void k_sweep(const ushort* __restrict__ xfh,
                                               const ushort* __restrict__ xfl,
                                               const ushort* __restrict__ efh,
                                               const ushort* __restrict__ efl,
                                               const float* __restrict__ en2,
                                               int* __restrict__ idxv,
                                               int* __restrict__ rlist,
                                               unsigned* __restrict__ rcnt) {
    __shared__ __align__(16) ushort As[16384];   // 32 KB: A-hi frags
    __shared__ __align__(16) ushort Al[16384];   // 32 KB: A-lo frags
    __shared__ __align__(16) float  Ds[256 * 64]; // 64 KB: D dump (xor-swizzled px)
    __shared__ float enSs[256];
    __shared__ ull   ltop[256][2];

    const int t = threadIdx.x, bid = blockIdx.x;
    const int p0 = bid << 6;
    const int w = t >> 6, lane = t & 63;
    const int quad = lane >> 4, l15 = lane & 15;

    // stage A hi+lo (identity copy of fragment-major global region)
    {
        const size_t base = (size_t)bid * 16384;
#pragma unroll
        for (int i = 0; i < 8; ++i) {
            const int off = (i * 256 + t) * 8;
            *(int4*)(&As[off]) = *(const int4*)(xfh + base + off);
            *(int4*)(&Al[off]) = *(const int4*)(xfl + base + off);
        }
    }
    __syncthreads();

    ull c1 = ~0ull, c2 = ~0ull;   // per-pixel running top-2 (threads t<64)

    for (int kt = 0; kt < 4; ++kt) {
        enSs[t] = en2[kt * 256 + t] * 1024.0f;   // guarded by the dump barrier

        const f4v z = {0.f, 0.f, 0.f, 0.f};
        f4v acc1[4][4], acc2[4][4];
#pragma unroll
        for (int mi = 0; mi < 4; ++mi)
#pragma unroll
            for (int ni = 0; ni < 4; ++ni) { acc1[mi][ni] = z; acc2[mi][ni] = z; }

#pragma unroll 2
        for (int dc = 0; dc < 8; ++dc) {
            h8 ah[4], al[4], bh[4], bl[4];
            const size_t bbase = ((size_t)((kt * 4 + w) * 8 + dc) * 4) * 512 + lane * 8;
#pragma unroll
            for (int ni = 0; ni < 4; ++ni) {
                bh[ni] = *(const h8*)(efh + bbase + ni * 512);
                bl[ni] = *(const h8*)(efl + bbase + ni * 512);
            }
            const int abase = dc * 2048 + lane * 8;
#pragma unroll
            for (int mi = 0; mi < 4; ++mi) {
                ah[mi] = *(const h8*)(&As[abase + mi * 512]);
                al[mi] = *(const h8*)(&Al[abase + mi * 512]);
            }
#pragma unroll
            for (int mi = 0; mi < 4; ++mi)
#pragma unroll
                for (int ni = 0; ni < 4; ++ni) {
                    acc1[mi][ni] = __builtin_amdgcn_mfma_f32_16x16x32_f16(
                        ah[mi], bh[ni], acc1[mi][ni], 0, 0, 0);
                    acc2[mi][ni] = __builtin_amdgcn_mfma_f32_16x16x32_f16(
                        ah[mi], bl[ni], acc2[mi][ni], 0, 0, 0);
                    acc2[mi][ni] = __builtin_amdgcn_mfma_f32_16x16x32_f16(
                        al[mi], bh[ni], acc2[mi][ni], 0, 0, 0);
                }
        }
        // ---- epilogue: dump all 256 codes, scan, merge ----
        __syncthreads();
#pragma unroll
        for (int mi = 0; mi < 4; ++mi)
#pragma unroll
            for (int ni = 0; ni < 4; ++ni) {
                const f4v cmb = acc1[mi][ni] + acc2[mi][ni] * (1.0f / 2048.0f);
                const int np = w * 64 + ni * 16 + l15;
                const int mb = mi * 16 + quad * 4;
                const int grp = (mb >> 2) ^ (np & 15);
                *(f4v*)(&Ds[np * 64 + grp * 4]) = cmb;
            }
        __syncthreads();
        {
            const int p = t & 63, cb0 = (t >> 6) * 64;
            ull k1 = ~0ull, k2 = ~0ull;
#pragma unroll 4
            for (int j = 0; j < 64; ++j) {
                const int np = cb0 + j;
                const int addr = np * 64 + ((((p >> 2) ^ (np & 15)) << 2) | (p & 3));
                const float D = fmaf(-2.0f, Ds[addr], enSs[np]);
                const ull key = ((ull)ordfix(__float_as_uint(D)) << 32) |
                                (unsigned)(kt * 256 + np);
                if (key < k1) { k2 = k1; k1 = key; }
                else if (key < k2) k2 = key;
            }
            ltop[t][0] = k1; ltop[t][1] = k2;
        }
        __syncthreads();
        if (t < 64) {
#pragma unroll
            for (int s = 0; s < 4; ++s) {
                const ull x1 = ltop[t + s * 64][0], x2 = ltop[t + s * 64][1];
                if (x1 < c1) { c2 = c1; c1 = x1; } else if (x1 < c2) c2 = x1;
                if (x2 < c1) { c2 = c1; c1 = x2; } else if (x2 < c2) c2 = x2;
            }
        }
    }
    if (t < 64) {
        const int k1 = (int)(unsigned)(c1 & 0xffffffffu);
        const float D1 = __uint_as_float(ordunfix((unsigned)(c1 >> 32)));
        const float D2 = __uint_as_float(ordunfix((unsigned)(c2 >> 32)));
        const int P = p0 + t;
        idxv[P] = k1;
        const bool risky = (D2 - D1) <= SWEEP_W;
        const ull mask = __ballot(risky);
        const int pre = __popcll(mask & ((1ull << t) - 1ull));
        unsigned base = 0;
        if (t == 0) base = atomicAdd(rcnt, (unsigned)__popcll(mask));
        base = (unsigned)__shfl((int)base, 0, 64);
        if (risky) rlist[base + pre] = P;
    }
}

// ---------------------------------------------------------------------------
// Exact f32 rescan of risky pixels (validated: replicates np ref numerics).
__global__ __launch_bounds__(256) void k_rescan(const float* __restrict__ x,
                                                const float* __restrict__ cb,
                                                const float* __restrict__ en2,
                                                const float* __restrict__ xn2,
                                                const int* __restrict__ rlist,
                                                const unsigned* __restrict__ rcnt,
                                                ull* __restrict__ rkey) {
    __shared__ float xs[64 * 68];
    __shared__ float es[64 * 132];
    __shared__ int plist[64];
    const int t = threadIdx.x;
    const unsigned cnt = *rcnt;
    const int nunits = (int)(((cnt + 63) >> 6) << 3);
    const int ti = t >> 4, tj = t & 15;

    for (int u = blockIdx.x; u < nunits; u += gridDim.x) {
        const int tile = u >> 3, kt = u & 7;
        __syncthreads();
        if (t < 64) {
            const int li = tile * 64 + t;
            plist[t] = rlist[li < (int)cnt ? li : 0];
        }
        __syncthreads();

        float xnr[4]; int pid[4];
#pragma unroll
        for (int r = 0; r < 4; ++r) {
            pid[r] = plist[ti * 4 + r];
            xnr[r] = xn2[pid[r]];
        }
        float acc[4][8];
#pragma unroll
        for (int r = 0; r < 4; ++r)
#pragma unroll
            for (int j = 0; j < 8; ++j) acc[r][j] = 0.f;
        float best_s[4]; int best_k[4];
#pragma unroll
        for (int r = 0; r < 4; ++r) { best_s[r] = INFINITY; best_k[r] = 0; }

        for (int dc = 0; dc < 4; ++dc) {
            __syncthreads();
            {
                const int p = t & 63, coff = t >> 6;
                const int P = plist[p];
                const float* xp = x + ((P >> 10) * 262144 + (P & 1023));
#pragma unroll
                for (int cc = 0; cc < 16; ++cc) {
                    const int cl = coff * 16 + cc;
                    xs[cl * 68 + p] = xp[(dc * 64 + cl) * 1024];
                }
            }
#pragma unroll
            for (int i = 0; i < 8; ++i) {
                const int jv = i * 256 + t, k = jv >> 4, d4 = (jv & 15) << 2;
                const float4 v = *(const float4*)(cb + (size_t)(kt * 128 + k) * 256 + dc * 64 + d4);
                es[(d4 + 0) * 132 + k] = v.x; es[(d4 + 1) * 132 + k] = v.y;
                es[(d4 + 2) * 132 + k] = v.z; es[(d4 + 3) * 132 + k] = v.w;
            }
            __syncthreads();
#pragma unroll 4
            for (int d = 0; d < 64; ++d) {
                const float4 xv = *(const float4*)(&xs[d * 68 + ti * 4]);
                const float4 e0 = *(const float4*)(&es[d * 132 + tj * 8]);
                const float4 e1 = *(const float4*)(&es[d * 132 + tj * 8 + 4]);
                const float xr[4] = {xv.x, xv.y, xv.z, xv.w};
                const float ej[8] = {e0.x, e0.y, e0.z, e0.w, e1.x, e1.y, e1.z, e1.w};
#pragma unroll
                for (int r = 0; r < 4; ++r)
#pragma unroll
                    for (int j = 0; j < 8; ++j)
                        acc[r][j] = fmaf(xr[r], ej[j], acc[r][j]);
            }
        }
#pragma unroll
        for (int j = 0; j < 8; ++j) {
            const int k = kt * 128 + tj * 8 + j;
            const float en = en2[k];
#pragma unroll
            for (int r = 0; r < 4; ++r) {
                const float s1 = xnr[r] + en;
                const float dist = fmaf(-2.f, acc[r][j], s1);
                if (dist < best_s[r] || (dist == best_s[r] && k < best_k[r])) {
                    best_s[r] = dist; best_k[r] = k;
                }
            }
        }
#pragma unroll
        for (int r = 0; r < 4; ++r) {
            float s = best_s[r]; int k = best_k[r];
            for (int m = 1; m < 16; m <<= 1) {
                const float s2 = __shfl_xor(s, m, 64);
                const int k2 = __shfl_xor(k, m, 64);
                if (s2 < s || (s2 == s && k2 < k)) { s = s2; k = k2; }
            }
            if (tj == 0 && (tile * 64 + ti * 4 + r) < (int)cnt) {
                const ull key = ((ull)__float_as_uint(s) << 32) | (unsigned)k;  // dist>0
                atomicMin(&rkey[pid[r]], key);
            }
        }
    }
}

// ---------------------------------------------------------------------------
// Gather (+resolve fused) -> q_out, (q-x)^2 sum, histogram, idx_f; the LAST
// block (device-scope done-counter) computes loss + perplexity.
__global__ __launch_bounds__(256) void k_gather(const float* __restrict__ x,
                                                const float* __restrict__ cb,
                                                const int* __restrict__ idxv,
                                                const ull* __restrict__ rkey,
                                                float* __restrict__ out,
                                                double* __restrict__ sumsq,
                                                unsigned* __restrict__ counts,
                                                unsigned* __restrict__ done) {
    __shared__ __align__(16) float cs[32 * 260];
    __shared__ int   kidx[32];
    __shared__ float wpart[4];
    __shared__ int   lastf;
    __shared__ double part[256];

    const int t = threadIdx.x, bid = blockIdx.x;
    const int n0 = bid * 32;
    if (t < 32) {
        const int n = n0 + t;
        const ull rk = rkey[n];
        const int kk = (rk != ~0ull) ? (int)(unsigned)(rk & 0xffffffffu) : idxv[n];
        kidx[t] = kk;
        atomicAdd(&counts[kk], 1u);
        out[IDX_OFF + n] = (float)kk;
    }
    if (t == 0) lastf = 0;
    __syncthreads();
#pragma unroll
    for (int i = 0; i < 8; ++i) {
        int jv = (i << 8) + t;
        int p = jv >> 6, c4 = (jv & 63) << 2;
        const float4 v = *(const float4*)(cb + (size_t)kidx[p] * 256 + c4);
        *(float4*)(&cs[p * 260 + c4]) = v;
    }
    __syncthreads();

    const int b = bid >> 5, h = bid & 31;
    const float* xb = x + b * 262144 + h * 32;
    float* qb = out + Q_OFF + b * 262144 + h * 32;

    float local = 0.f;
#pragma unroll
    for (int i = 0; i < 8; ++i) {
        int j = (i << 8) + t;
        int c = j >> 3, w4 = (j & 7) << 2;
        const float q0 = cs[(w4 + 0) * 260 + c];
        const float q1 = cs[(w4 + 1) * 260 + c];
        const float q2 = cs[(w4 + 2) * 260 + c];
        const float q3 = cs[(w4 + 3) * 260 + c];
        const float4 xv = *(const float4*)(xb + c * 1024 + w4);
        const float d0 = q0 - xv.x, d1 = q1 - xv.y;
        const float d2 = q2 - xv.z, d3 = q3 - xv.w;
        local += d0 * d0 + d1 * d1 + d2 * d2 + d3 * d3;
        qb[c * 1024 + w4 + 0] = q0;
        qb[c * 1024 + w4 + 1] = q1;
        qb[c * 1024 + w4 + 2] = q2;
        qb[c * 1024 + w4 + 3] = q3;
    }
    for (int m = 32; m > 0; m >>= 1) local += __shfl_down(local, m, 64);
    if ((t & 63) == 0) wpart[t >> 6] = local;
    __syncthreads();
    if (t == 0) {
        const float bs = wpart[0] + wpart[1] + wpart[2] + wpart[3];
        atomicAdd(sumsq, (double)bs);
        __threadfence();
        if (atomicAdd(done, 1u) == 1023u) lastf = 1;
    }
    __syncthreads();
    if (lastf) {
        double s = 0.0;
        for (int k = t; k < K_; k += 256) {
            const unsigned c = atomicAdd(&counts[k], 0u);   // coherent read
            const double p = (double)c / (double)N_;
            s += p * log(p + 1e-10);
        }
        part[t] = s;
        __syncthreads();
        for (int off = 128; off > 0; off >>= 1) {
            if (t < off) part[t] += part[t + off];
            __syncthreads();
        }
        if (t == 0) {
            const double ss = atomicAdd(sumsq, 0.0);        // coherent read
            out[PERP_OFF] = (float)exp(-part[0]);
            out[0] = (float)(ss * 1.25 / (double)NELEM);
        }
    }
}

// ---------------------------------------------------------------------------
extern "C" void kernel_launch(void* const* d_in, const int* in_sizes, int n_in,
                              void* d_out, int out_size, void* d_ws, size_t ws_size,
                              hipStream_t stream) {
    const float* x  = (const float*)d_in[0];
    const float* cb = (const float*)d_in[1];
    float* out = (float*)d_out;
    char*  ws  = (char*)d_ws;

    unsigned* counts = (unsigned*)(ws + WS_COUNTS);
    double*   sumsq  = (double*)(ws + WS_SUMSQ);
    unsigned* rcnt   = (unsigned*)(ws + WS_RISKCNT);
    unsigned* done   = (unsigned*)(ws + WS_DONE);
    float*    en2    = (float*)(ws + WS_EN2);
    float*    xn2    = (float*)(ws + WS_XN2);
    int*      idxv   = (int*)(ws + WS_IDX);
    int*      rlist  = (int*)(ws + WS_RLIST);
    ull*      rkey   = (ull*)(ws + WS_RKEY);
    ushort*   efh    = (ushort*)(ws + WS_EHI);
    ushort*   xfh    = (ushort*)(ws + WS_XHI);
    ushort*   xfl    = (ushort*)(out + XLO_F_OFF);   // d_out Q region scratch
    ushort*   efl    = (ushort*)(out + ELO_F_OFF);

    k_pre<<<592, 256, 0, stream>>>(x, cb, xfh, xfl, xn2, efh, efl, en2,
                                   rkey, counts, rcnt, done, sumsq);
    k_sweep<<<512, 256, 0, stream>>>(xfh, xfl, efh, efl, en2, idxv, rlist, rcnt);
    k_rescan<<<512, 256, 0, stream>>>(x, cb, en2, xn2, rlist, rcnt, rkey);
    k_gather<<<1024, 256, 0, stream>>>(x, cb, idxv, rkey, out, sumsq, counts, done);
}

// Round 6
// 244.393 us; speedup vs baseline: 1.4667x; 1.1910x over previous
//
#include <hip/hip_runtime.h>
#include <math.h>

// Problem constants
#define K_    1024
#define N_    32768
#define NELEM 8388608

// d_out layout (floats, reference return order)
#define Q_OFF    1
#define PERP_OFF 8388609
#define IDX_OFF  8388610

// d_out Q-region scratch (overwritten by k_gather at the end)
#define XLO_F_OFF 4          // xlo frag: 32768*256 fp16

typedef unsigned long long ull;
typedef _Float16 h8  __attribute__((ext_vector_type(8)));
typedef float    f4v __attribute__((ext_vector_type(4)));

// ws layout (bytes)
#define WS_COUNTS  0        // 1024 u32
#define WS_SUMSQ   4096     // double
#define WS_RISKCNT 4104     // u32
#define WS_DONE    4108     // u32
#define WS_EN2     4160     // 1024 f32
#define WS_XN2     8256     // 32768 f32
#define WS_IDX     139328   // 32768 i32
#define WS_RLIST   270400   // 32768 i32
#define WS_RKEY    401472   // 32768 u64
#define WS_EHI     663616   // 1024*256 fp16 (fragment-major)
#define WS_XHI     1187904  // 32768*256 fp16 (fragment-major)

// risky-gap threshold, quantized (1/1024-scaled-distance grid):
// W = 0.20 scaled -> 205 grid + 2 quantization slack. Covers ref f32
// rounding (0.066) + 2x sweep dot error (max ~0.027 at 6 sigma; 15 sigma
// would be needed to break 0.134). Flagged pixels get exact f32 rescan.
#define RISKY_Q 207u

__device__ __forceinline__ unsigned u32min(unsigned a, unsigned b) { return a < b ? a : b; }
__device__ __forceinline__ unsigned u32max(unsigned a, unsigned b) { return a > b ? a : b; }

// ---------------------------------------------------------------------------
// k_pre: blocks 0..511: x -> fragment-major fp16 hi/lo + xn2.
//        blocks 512..527: codebook -> fragment-major fp16 hi + en2.
//        blocks 528..591: rkey init (+ block 528: counts/rcnt/done/sumsq).
// Fragment layout (halfwords):
//   xf: [pixblock 512][dc 8][pi 4][lane 64][j 8]; pixel=pi*16+(lane&15),
//       d = dc*32 + (lane>>4)*8 + j
//   ef: [kt 4][w 4][dc 8][ci 4][lane 64][j 8]; code=kt*256+w*64+ci*16+(lane&15)
__global__ __launch_bounds__(256) void k_pre(const float* __restrict__ x,
                                             const float* __restrict__ cb,
                                             ushort* __restrict__ xfh,
                                             ushort* __restrict__ xfl,
                                             float* __restrict__ xn2,
                                             ushort* __restrict__ efh,
                                             float* __restrict__ en2,
                                             ull* __restrict__ rkey,
                                             unsigned* __restrict__ counts,
                                             unsigned* __restrict__ rcnt,
                                             unsigned* __restrict__ done,
                                             double* __restrict__ sumsq) {
    __shared__ float T[256 * 68];
    __shared__ double red[256];
    const int t = threadIdx.x, bid = blockIdx.x;

    if (bid < 512) {
        const int b = bid >> 4, hw0 = (bid & 15) << 6;
        const float* xb = x + b * 262144 + hw0;
        // stage [c][p], quad-swizzled so frag reads are <=2-way bank aliased
#pragma unroll
        for (int i = 0; i < 16; ++i) {
            const int jv = i * 256 + t, c = jv >> 4, p4 = (jv & 15) << 2;
            const int sw = ((c >> 3) & 3) << 3;
            *(float4*)(&T[c * 68 + (p4 ^ sw)]) = *(const float4*)(xb + c * 1024 + p4);
        }
        __syncthreads();
        const int mi = t >> 6, lane = t & 63;
        const int quad = (t >> 4) & 3, l15 = t & 15;
        const int pxs = (mi * 16 + l15) ^ (quad << 3);
        double sn = 0.0;
        const size_t obase = (size_t)bid * 16384 + lane * 8;
#pragma unroll
        for (int dc = 0; dc < 8; ++dc) {
            union { _Float16 h[8]; int4 v; } ph, pl;
#pragma unroll
            for (int j = 0; j < 8; ++j) {
                const float v = T[(dc * 32 + quad * 8 + j) * 68 + pxs];
                sn += (double)v * v;
                const _Float16 hi = (_Float16)v;
                ph.h[j] = hi;
                pl.h[j] = (_Float16)((v - (float)hi) * 2048.0f);
            }
            *(int4*)(xfh + obase + (dc * 4 + mi) * 512) = ph.v;
            *(int4*)(xfl + obase + (dc * 4 + mi) * 512) = pl.v;
        }
        red[t] = sn;
        __syncthreads();
        if (t < 64) {
            const int base = (t >> 4) * 64 + (t & 15);
            xn2[bid * 64 + t] = (float)(red[base] + red[base + 16] +
                                        red[base + 32] + red[base + 48]);
        }
    } else if (bid < 528) {
        const int n = (bid - 512) * 64 + (t >> 2);
        const int seg = t & 3;
        const float* src = cb + (size_t)n * 256 + seg * 64;
        const int kt = n >> 8, wch = (n >> 6) & 3, ci = (n >> 4) & 3, l15 = n & 15;
        double s = 0.0;
#pragma unroll
        for (int g = 0; g < 8; ++g) {
            const float4 a = *(const float4*)(src + g * 8);
            const float4 b = *(const float4*)(src + g * 8 + 4);
            s += (double)a.x * a.x + (double)a.y * a.y + (double)a.z * a.z + (double)a.w * a.w;
            s += (double)b.x * b.x + (double)b.y * b.y + (double)b.z * b.z + (double)b.w * b.w;
            const float v[8] = {a.x, a.y, a.z, a.w, b.x, b.y, b.z, b.w};
            union { _Float16 h[8]; int4 q; } ph;
#pragma unroll
            for (int j = 0; j < 8; ++j)
                ph.h[j] = (_Float16)(v[j] * 1024.0f);          // exact pow2 scale
            const int dc = seg * 2 + (g >> 2);
            const int quad = g & 3;
            const size_t addr = ((size_t)(((kt * 4 + wch) * 8 + dc) * 4 + ci) * 64 +
                                 (quad * 16 + l15)) * 8;
            *(int4*)(efh + addr) = ph.q;
        }
        red[t] = s;
        __syncthreads();
        if (t < 64) {
            const int r2 = (bid - 512) * 64 + t;
            en2[r2] = (float)(red[t * 4] + red[t * 4 + 1] + red[t * 4 + 2] + red[t * 4 + 3]);
        }
    } else {
        const int ib = bid - 528;
        const int i0 = ib * 512 + t * 2;
        rkey[i0] = ~0ull; rkey[i0 + 1] = ~0ull;
        if (ib == 0) {
            ((uint4*)counts)[t] = make_uint4(0u, 0u, 0u, 0u);
            if (t == 0) { *rcnt = 0u; *done = 0u; *sumsq = 0.0; }
        }
    }
}

// ---------------------------------------------------------------------------
// 2-chain fp16 MFMA sweep, register epilogue. A = codes (rows), B = pixels
// (cols). Block = 64 px x 1024 codes; wave w = codes [kt*256+w*64, +64).
// D layout: col(lane&15)=pixel, row(quad*4+reg)=code -> each lane owns 4
// pixels x 16 codes: per-pixel top-2 in registers as quantized u32 keys.
// dist_s = en_s - 2*(eh.xh + eh.xl/2048); key = (trunc((dist+128)*1024)<<10)|code.
// Zero barriers in the K-loop; 1 staging + 1 merge barrier total.
__global__ __launch_bounds__(256, 2) void k_sweep(const ushort* __restrict__ xfh,
                                                  const ushort* __restrict__ xfl,
                                                  const ushort* __restrict__ efh,
                                                  const float* __restrict__ en2,
                                                  int* __restrict__ idxv,
                                                  int* __restrict__ rlist,
                                                  unsigned* __restrict__ rcnt) {
    __shared__ __align__(16) ushort Bsh[16384];   // 32 KB: pixel-hi frags
    __shared__ __align__(16) ushort Bsl[16384];   // 32 KB: pixel-lo frags
    __shared__ __align__(16) float  enS[1024];    // 4 KB: scaled code norms
    __shared__ unsigned Mg[4][64][2];             // 2 KB: per-wave top-2

    const int t = threadIdx.x, bid = blockIdx.x;
    const int p0 = bid << 6;
    const int w = t >> 6, lane = t & 63;
    const int quad = lane >> 4, l15 = lane & 15;

    {   // stage this block's 64 pixels (hi+lo) + scaled norms
        const size_t base = (size_t)bid * 16384;
#pragma unroll
        for (int i = 0; i < 8; ++i) {
            const int off = (i * 256 + t) * 8;
            *(int4*)(&Bsh[off]) = *(const int4*)(xfh + base + off);
            *(int4*)(&Bsl[off]) = *(const int4*)(xfl + base + off);
        }
#pragma unroll
        for (int i = 0; i < 4; ++i)
            enS[i * 256 + t] = en2[i * 256 + t] * 1024.0f;
    }
    __syncthreads();

    unsigned K1[4], K2[4];   // running top-2 per pixel (ni*16+l15)
#pragma unroll
    for (int ni = 0; ni < 4; ++ni) { K1[ni] = 0xFFFFFFFFu; K2[ni] = 0xFFFFFFFFu; }

    for (int kt = 0; kt < 4; ++kt) {
        const f4v z = {0.f, 0.f, 0.f, 0.f};
        f4v acc1[4][4], acc2[4][4];
#pragma unroll
        for (int mi = 0; mi < 4; ++mi)
#pragma unroll
            for (int ni = 0; ni < 4; ++ni) { acc1[mi][ni] = z; acc2[mi][ni] = z; }

#pragma unroll 2
        for (int dc = 0; dc < 8; ++dc) {
            h8 ah[4], bh[4], bl[4];
            const size_t abase = ((size_t)((kt * 4 + w) * 8 + dc) * 4) * 512 + lane * 8;
#pragma unroll
            for (int mi = 0; mi < 4; ++mi)
                ah[mi] = *(const h8*)(efh + abase + mi * 512);
            const int bbase = dc * 2048 + lane * 8;
#pragma unroll
            for (int ni = 0; ni < 4; ++ni) {
                bh[ni] = *(const h8*)(&Bsh[bbase + ni * 512]);
                bl[ni] = *(const h8*)(&Bsl[bbase + ni * 512]);
            }
#pragma unroll
            for (int mi = 0; mi < 4; ++mi)
#pragma unroll
                for (int ni = 0; ni < 4; ++ni) {
                    acc1[mi][ni] = __builtin_amdgcn_mfma_f32_16x16x32_f16(
                        ah[mi], bh[ni], acc1[mi][ni], 0, 0, 0);
                    acc2[mi][ni] = __builtin_amdgcn_mfma_f32_16x16x32_f16(
                        ah[mi], bl[ni], acc2[mi][ni], 0, 0, 0);
                }
        }
        // register epilogue: 64 dists -> quantized keys -> top-2 per pixel
#pragma unroll
        for (int mi = 0; mi < 4; ++mi) {
            const int cbase = kt * 256 + w * 64 + mi * 16 + quad * 4;
            const f4v en4 = *(const f4v*)(&enS[cbase]);   // b128, broadcast/2-way
#pragma unroll
            for (int ni = 0; ni < 4; ++ni) {
#pragma unroll
                for (int r = 0; r < 4; ++r) {
                    const float cmb = acc1[mi][ni][r] + acc2[mi][ni][r] * (1.0f / 2048.0f);
                    const float dist = fmaf(-2.0f, cmb, en4[r]);
                    float qf = fmaf(dist, 1024.0f, 131072.0f);
                    qf = fminf(fmaxf(qf, 0.0f), 524287.0f);
                    const unsigned key = ((unsigned)(int)qf << 10) | (unsigned)(cbase + r);
                    const unsigned o1 = K1[ni];
                    K1[ni] = u32min(o1, key);
                    K2[ni] = u32min(K2[ni], u32max(o1, key));
                }
            }
        }
    }
    // cross-quad merge (disjoint code sets, same pixels): xor 16, 32
#pragma unroll
    for (int m = 16; m <= 32; m <<= 1) {
#pragma unroll
        for (int ni = 0; ni < 4; ++ni) {
            const unsigned a1 = (unsigned)__shfl_xor((int)K1[ni], m, 64);
            const unsigned a2 = (unsigned)__shfl_xor((int)K2[ni], m, 64);
            const unsigned n1 = u32min(K1[ni], a1);
            const unsigned n2 = u32min(u32max(K1[ni], a1), u32min(K2[ni], a2));
            K1[ni] = n1; K2[ni] = n2;
        }
    }
    if (quad == 0) {
#pragma unroll
        for (int ni = 0; ni < 4; ++ni) {
            Mg[w][ni * 16 + l15][0] = K1[ni];
            Mg[w][ni * 16 + l15][1] = K2[ni];
        }
    }
    __syncthreads();
    if (t < 64) {   // cross-wave merge (disjoint code sets per wave)
        unsigned b1 = Mg[0][t][0], b2 = Mg[0][t][1];
#pragma unroll
        for (int ww = 1; ww < 4; ++ww) {
            const unsigned a1 = Mg[ww][t][0], a2 = Mg[ww][t][1];
            const unsigned n1 = u32min(b1, a1);
            b2 = u32min(u32max(b1, a1), u32min(b2, a2));
            b1 = n1;
        }
        const int P = p0 + t;
        idxv[P] = (int)(b1 & 1023u);
        const bool risky = ((b2 >> 10) - (b1 >> 10)) <= RISKY_Q;
        const ull mask = __ballot(risky);
        const int pre = __popcll(mask & ((1ull << t) - 1ull));
        unsigned base = 0;
        if (t == 0) base = atomicAdd(rcnt, (unsigned)__popcll(mask));
        base = (unsigned)__shfl((int)base, 0, 64);
        if (risky) rlist[base + pre] = P;
    }
}

// ---------------------------------------------------------------------------
// Exact f32 rescan of risky pixels (validated: replicates np ref numerics).
__global__ __launch_bounds__(256) void k_rescan(const float* __restrict__ x,
                                                const float* __restrict__ cb,
                                                const float* __restrict__ en2,
                                                const float* __restrict__ xn2,
                                                const int* __restrict__ rlist,
                                                const unsigned* __restrict__ rcnt,
                                                ull* __restrict__ rkey) {
    __shared__ float xs[64 * 68];
    __shared__ float es[64 * 132];
    __shared__ int plist[64];
    const int t = threadIdx.x;
    const unsigned cnt = *rcnt;
    const int nunits = (int)(((cnt + 63) >> 6) << 3);
    const int ti = t >> 4, tj = t & 15;

    for (int u = blockIdx.x; u < nunits; u += gridDim.x) {
        const int tile = u >> 3, kt = u & 7;
        __syncthreads();
        if (t < 64) {
            const int li = tile * 64 + t;
            plist[t] = rlist[li < (int)cnt ? li : 0];
        }
        __syncthreads();

        float xnr[4]; int pid[4];
#pragma unroll
        for (int r = 0; r < 4; ++r) {
            pid[r] = plist[ti * 4 + r];
            xnr[r] = xn2[pid[r]];
        }
        float acc[4][8];
#pragma unroll
        for (int r = 0; r < 4; ++r)
#pragma unroll
            for (int j = 0; j < 8; ++j) acc[r][j] = 0.f;
        float best_s[4]; int best_k[4];
#pragma unroll
        for (int r = 0; r < 4; ++r) { best_s[r] = INFINITY; best_k[r] = 0; }

        for (int dc = 0; dc < 4; ++dc) {
            __syncthreads();
            {
                const int p = t & 63, coff = t >> 6;
                const int P = plist[p];
                const float* xp = x + ((P >> 10) * 262144 + (P & 1023));
#pragma unroll
                for (int cc = 0; cc < 16; ++cc) {
                    const int cl = coff * 16 + cc;
                    xs[cl * 68 + p] = xp[(dc * 64 + cl) * 1024];
                }
            }
#pragma unroll
            for (int i = 0; i < 8; ++i) {
                const int jv = i * 256 + t, k = jv >> 4, d4 = (jv & 15) << 2;
                const float4 v = *(const float4*)(cb + (size_t)(kt * 128 + k) * 256 + dc * 64 + d4);
                es[(d4 + 0) * 132 + k] = v.x; es[(d4 + 1) * 132 + k] = v.y;
                es[(d4 + 2) * 132 + k] = v.z; es[(d4 + 3) * 132 + k] = v.w;
            }
            __syncthreads();
#pragma unroll 4
            for (int d = 0; d < 64; ++d) {
                const float4 xv = *(const float4*)(&xs[d * 68 + ti * 4]);
                const float4 e0 = *(const float4*)(&es[d * 132 + tj * 8]);
                const float4 e1 = *(const float4*)(&es[d * 132 + tj * 8 + 4]);
                const float xr[4] = {xv.x, xv.y, xv.z, xv.w};
                const float ej[8] = {e0.x, e0.y, e0.z, e0.w, e1.x, e1.y, e1.z, e1.w};
#pragma unroll
                for (int r = 0; r < 4; ++r)
#pragma unroll
                    for (int j = 0; j < 8; ++j)
                        acc[r][j] = fmaf(xr[r], ej[j], acc[r][j]);
            }
        }
#pragma unroll
        for (int j = 0; j < 8; ++j) {
            const int k = kt * 128 + tj * 8 + j;
            const float en = en2[k];
#pragma unroll
            for (int r = 0; r < 4; ++r) {
                const float s1 = xnr[r] + en;
                const float dist = fmaf(-2.f, acc[r][j], s1);
                if (dist < best_s[r] || (dist == best_s[r] && k < best_k[r])) {
                    best_s[r] = dist; best_k[r] = k;
                }
            }
        }
#pragma unroll
        for (int r = 0; r < 4; ++r) {
            float s = best_s[r]; int k = best_k[r];
            for (int m = 1; m < 16; m <<= 1) {
                const float s2 = __shfl_xor(s, m, 64);
                const int k2 = __shfl_xor(k, m, 64);
                if (s2 < s || (s2 == s && k2 < k)) { s = s2; k = k2; }
            }
            if (tj == 0 && (tile * 64 + ti * 4 + r) < (int)cnt) {
                const ull key = ((ull)__float_as_uint(s) << 32) | (unsigned)k;  // dist>0
                atomicMin(&rkey[pid[r]], key);
            }
        }
    }
}

// ---------------------------------------------------------------------------
// Gather (+resolve fused) -> q_out, (q-x)^2 sum, histogram, idx_f; the LAST
// block (device-scope done-counter) computes loss + perplexity.
__global__ __launch_bounds__(256) void k_gather(const float* __restrict__ x,
                                                const float* __restrict__ cb,
                                                const int* __restrict__ idxv,
                                                const ull* __restrict__ rkey,
                                                float* __restrict__ out,
                                                double* __restrict__ sumsq,
                                                unsigned* __restrict__ counts,
                                                unsigned* __restrict__ done) {
    __shared__ __align__(16) float cs[32 * 260];
    __shared__ int   kidx[32];
    __shared__ float wpart[4];
    __shared__ int   lastf;
    __shared__ double part[256];

    const int t = threadIdx.x, bid = blockIdx.x;
    const int n0 = bid * 32;
    if (t < 32) {
        const int n = n0 + t;
        const ull rk = rkey[n];
        const int kk = (rk != ~0ull) ? (int)(unsigned)(rk & 0xffffffffu) : idxv[n];
        kidx[t] = kk;
        atomicAdd(&counts[kk], 1u);
        out[IDX_OFF + n] = (float)kk;
    }
    if (t == 0) lastf = 0;
    __syncthreads();
#pragma unroll
    for (int i = 0; i < 8; ++i) {
        int jv = (i << 8) + t;
        int p = jv >> 6, c4 = (jv & 63) << 2;
        const float4 v = *(const float4*)(cb + (size_t)kidx[p] * 256 + c4);
        *(float4*)(&cs[p * 260 + c4]) = v;
    }
    __syncthreads();

    const int b = bid >> 5, h = bid & 31;
    const float* xb = x + b * 262144 + h * 32;
    float* qb = out + Q_OFF + b * 262144 + h * 32;

    float local = 0.f;
#pragma unroll
    for (int i = 0; i < 8; ++i) {
        int j = (i << 8) + t;
        int c = j >> 3, w4 = (j & 7) << 2;
        const float q0 = cs[(w4 + 0) * 260 + c];
        const float q1 = cs[(w4 + 1) * 260 + c];
        const float q2 = cs[(w4 + 2) * 260 + c];
        const float q3 = cs[(w4 + 3) * 260 + c];
        const float4 xv = *(const float4*)(xb + c * 1024 + w4);
        const float d0 = q0 - xv.x, d1 = q1 - xv.y;
        const float d2 = q2 - xv.z, d3 = q3 - xv.w;
        local += d0 * d0 + d1 * d1 + d2 * d2 + d3 * d3;
        qb[c * 1024 + w4 + 0] = q0;
        qb[c * 1024 + w4 + 1] = q1;
        qb[c * 1024 + w4 + 2] = q2;
        qb[c * 1024 + w4 + 3] = q3;
    }
    for (int m = 32; m > 0; m >>= 1) local += __shfl_down(local, m, 64);
    if ((t & 63) == 0) wpart[t >> 6] = local;
    __syncthreads();
    if (t == 0) {
        const float bs = wpart[0] + wpart[1] + wpart[2] + wpart[3];
        atomicAdd(sumsq, (double)bs);
        __threadfence();
        if (atomicAdd(done, 1u) == 1023u) lastf = 1;
    }
    __syncthreads();
    if (lastf) {
        double s = 0.0;
        for (int k = t; k < K_; k += 256) {
            const unsigned c = atomicAdd(&counts[k], 0u);   // coherent read
            const double p = (double)c / (double)N_;
            s += p * log(p + 1e-10);
        }
        part[t] = s;
        __syncthreads();
        for (int off = 128; off > 0; off >>= 1) {
            if (t < off) part[t] += part[t + off];
            __syncthreads();
        }
        if (t == 0) {
            const double ss = atomicAdd(sumsq, 0.0);        // coherent read
            out[PERP_OFF] = (float)exp(-part[0]);
            out[0] = (float)(ss * 1.25 / (double)NELEM);
        }
    }
}

// ---------------------------------------------------------------------------
extern "C" void kernel_launch(void* const* d_in, const int* in_sizes, int n_in,
                              void* d_out, int out_size, void* d_ws, size_t ws_size,
                              hipStream_t stream) {
    const float* x  = (const float*)d_in[0];
    const float* cb = (const float*)d_in[1];
    float* out = (float*)d_out;
    char*  ws  = (char*)d_ws;

    unsigned* counts = (unsigned*)(ws + WS_COUNTS);
    double*   sumsq  = (double*)(ws + WS_SUMSQ);
    unsigned* rcnt   = (unsigned*)(ws + WS_RISKCNT);
    unsigned* done   = (unsigned*)(ws + WS_DONE);
    float*    en2    = (float*)(ws + WS_EN2);
    float*    xn2    = (float*)(ws + WS_XN2);
    int*      idxv   = (int*)(ws + WS_IDX);
    int*      rlist  = (int*)(ws + WS_RLIST);
    ull*      rkey   = (ull*)(ws + WS_RKEY);
    ushort*   efh    = (ushort*)(ws + WS_EHI);
    ushort*   xfh    = (ushort*)(ws + WS_XHI);
    ushort*   xfl    = (ushort*)(out + XLO_F_OFF);   // d_out Q region scratch

    k_pre<<<592, 256, 0, stream>>>(x, cb, xfh, xfl, xn2, efh, en2,
                                   rkey, counts, rcnt, done, sumsq);
    k_sweep<<<512, 256, 0, stream>>>(xfh, xfl, efh, en2, idxv, rlist, rcnt);
    k_rescan<<<512, 256, 0, stream>>>(x, cb, en2, xn2, rlist, rcnt, rkey);
    k_gather<<<1024, 256, 0, stream>>>(x, cb, idxv, rkey, out, sumsq, counts, done);
}